// Round 5
// baseline (333.295 us; speedup 1.0000x reference)
//
#include <hip/hip_runtime.h>

typedef unsigned short u16;
typedef __attribute__((ext_vector_type(8))) short bf16x8;   // 8 x bf16 (4 VGPRs)
typedef __attribute__((ext_vector_type(4))) float f32x4;

#define NLEV 5
#define CCH 256
#define KTOT 2304            // 9 taps * 256 ci
#define P_TOT 8525           // sum HW
#define PP_TOT 9165          // sum (H+2)*(W+2)
#define PLS (PP_TOT*64)      // activation plane stride (u16), 4 planes of 64 ci
#define HSTR 11776           // halo LDS plane stride (u16) = 23 slabs * 512

__constant__ int   c_HW[NLEV]     = {6400, 1600, 400, 100, 25};
__constant__ int   c_W[NLEV]      = {80, 40, 20, 10, 5};    // H == W (square)
__constant__ int   c_off[NLEV]    = {0, 6400, 8000, 8400, 8500};
__constant__ int   c_poff[NLEV]   = {0, 6724, 8488, 8972, 9116};
__constant__ int   c_tls[NLEV+1]  = {0, 50, 65, 71, 73, 74};  // 16x8 tile starts
__constant__ int   c_ntx[NLEV]    = {5, 3, 2, 1, 1};          // tiles across
__constant__ float c_stridef[NLEV]= {8.f, 16.f, 32.f, 64.f, 128.f};

__device__ __forceinline__ u16 f2bf(float f){
  union { float f; unsigned u; } v; v.f = f;
  unsigned r = v.u + 0x7fffu + ((v.u >> 16) & 1u);   // RNE
  return (u16)(r >> 16);
}

// async global->LDS: 64 lanes x 16B; HW writes lane i to ldsbase + i*16.
__device__ __forceinline__ void g2l16(const u16* g, u16* l, int lane){
#if defined(__has_builtin)
#if __has_builtin(__builtin_amdgcn_global_load_lds)
  __builtin_amdgcn_global_load_lds(
      (const __attribute__((address_space(1))) unsigned int*)g,
      (__attribute__((address_space(3))) unsigned int*)l, 16, 0, 0);
  return;
#endif
#endif
  *(uint4*)(l + lane*8) = *(const uint4*)g;  // fallback: sync copy
}

// s_waitcnt imm (gfx9: vm[3:0] bits3:0, vm[5:4] bits15:14, exp[6:4], lgkm[11:8])
#define WAIT_VM12  0x0F7C   // vmcnt(12): allow this titer's A batch in flight

// ---------------------------------------------------------------------------
// R5: XCD-pinned weight locality (T1). R2-R4 all flat at ~329 us; towers are
// ~45 us/dispatch = single co-resident block-wave whose titers each eat an
// L3-latency A-load miss: the default linear-id dispatch (id = ptile +
// 74*(mtile+4*br)) round-robins consecutive PTILES across XCDs, so the 74
// blocks sharing one 1.2 MB weight slice are spread over all 8 XCDs and
// every XCD L2 (4 MB) must hold the full 9.4 MB weight set + streams ->
// thrash to L3/HBM; the 1-titer A register prefetch (~500 cyc) cannot cover
// ~600-900 cyc latency. Fix: 1-D grid of 592 = 74*8, decode
//   comb = bid & 7  -> (mtile = comb & 3, br = comb >> 2),  ptile = bid >> 3
// With round-robin wg->XCD (id % 8), all blocks of one (mtile,br) land on
// ONE XCD: per-XCD weights 1.2 MB = L2-resident, A-loads ~200-cyc hits,
// covered by the prefetch. Bijective remap -> output-identical.
// K-loop per wave (unchanged from R4): 12 titers u=(cc,dw); B rows 0..9
// read once per sub, reused across 3 dh taps; A frags double-buffered
// (afA/afB, static indices); halo plane dbuf in LDS, barriers at u=3,6,9
// with WAIT_VM12 proving the previous stageH landed (in-order retirement).
// MODE 0: towers, grid (592), 128 thr; GN stats fused in epilogue.
// MODE 1: heads, grid (74,3,1): job y=0: br0 co0-63; y=1: br0 co64-127
//         (m<80 guard); y=2: br1 co0-63 (pred m<4 + iou m==4).
// ---------------------------------------------------------------------------
template<int MODE>
__global__ __launch_bounds__(128, 2) void gemm_conv(
    const u16* __restrict__ Xc, const u16* __restrict__ Xb,
    const u16* __restrict__ Wc, const u16* __restrict__ Wb,
    const float* __restrict__ bc, const float* __restrict__ bb,
    float* __restrict__ Yc, float* __restrict__ Yb,
    float* __restrict__ stats,
    const float* __restrict__ predb, const float* __restrict__ ioub,
    const float* __restrict__ scales, float* __restrict__ out)
{
  __shared__ u16 hB[2*HSTR];        // 47104 B: halo plane dbuf (slot = cc&1)
  __shared__ float sstat[8][2];     // 64 B

  const int bid   = blockIdx.x;
  const int ptile = (MODE == 0) ? (bid >> 3) : bid;
  const int job   = (MODE == 0) ? 0 : blockIdx.y;
  const int mtile = (MODE == 0) ? (bid & 3) : (job == 1 ? 1 : 0);
  const int br    = (MODE == 0) ? ((bid >> 2) & 1) : (job == 2 ? 1 : 0);
  int lv = 0;
  #pragma unroll
  for (int i = 1; i < NLEV; i++) if (ptile >= c_tls[i]) lv = i;
  const int tidx = ptile - c_tls[lv];
  const int ntx = c_ntx[lv];
  const int ty0 = (tidx / ntx) * 8, tx0 = (tidx - (tidx / ntx) * ntx) * 16;
  const int W = c_W[lv], wrow2 = W + 2;

  const int tid = threadIdx.x, wv = tid >> 6, ln = tid & 63;
  const int quad = ln >> 4, l15 = ln & 15;

  const u16* __restrict__ X  = br ? Xb : Xc;   // planar activations
  const u16* __restrict__ WA = br ? Wb : Wc;   // packed weights

  const int SZ = (MODE == 0) ? 16384 : 8192;   // per-stage A u16s
  const int g2 = mtile*2 + wv;                 // 32-co group index
  const u16* aln = WA + (size_t)(g2*2048 + ln*8);

  // Halo per-lane source pointers: slab j = wv+2i (j>22 -> idempotent dup of
  // this wave's previous slab so every wave issues exactly 12 loads).
  const u16* hptr[12]; int hslab[12];
  #pragma unroll
  for (int i = 0; i < 12; i++) {
    int j = wv + 2*i;
    if (j > 22) j -= 2;                        // wv1,i=11 -> slab 21 (dup)
    hslab[i] = j;
    const int item = j*64 + ln;
    int hp = item >> 3; if (hp >= 180) hp -= 180;
    const int g = item & 7;
    const int hy = hp / 18, hx = hp - hy*18;
    const int prow = c_poff[lv] + (ty0 + hy)*wrow2 + tx0 + hx;
    hptr[i] = X + (size_t)prow*64 + ((g ^ (hp & 7)) << 3);
  }

  auto stageH = [&](int plane) {               // 12 loads/wave
    u16* dst = &hB[(plane & 1) * HSTR];
    const size_t cof = (size_t)plane * PLS;
    #pragma unroll
    for (int i = 0; i < 12; i++)
      g2l16(hptr[i] + cof, dst + hslab[i]*512, ln);
  };

  f32x4 acc[2][8];
  #pragma unroll
  for (int i = 0; i < 2; i++)
    #pragma unroll
    for (int j = 0; j < 8; j++) acc[i][j] = (f32x4){0.f, 0.f, 0.f, 0.f};

  // A fragment DOUBLE BUFFER: [dh][sub][mt] x2 = 96 VGPR. Static indexing
  // only (rule #20): the two sets alternate via a 2-step unrolled loop.
  bf16x8 afA[3][2][2], afB[3][2][2];
  auto loadA = [&](int cc_, int dw_, bf16x8 (&af)[3][2][2]) {
    #pragma unroll
    for (int dh = 0; dh < 3; dh++) {
      const u16* p = aln + (size_t)((dh*3 + dw_)*4 + cc_) * SZ;
      #pragma unroll
      for (int sub = 0; sub < 2; sub++)
        #pragma unroll
        for (int mt = 0; mt < 2; mt++)
          af[dh][sub][mt] = *(const bf16x8*)(p + (sub*2 + mt)*512);
    }
  };

  if (MODE == 0 && tid < 16) sstat[tid >> 1][tid & 1] = 0.f;

  // ---- prologue: halo planes 0,1 + A(0) into afA; one barrier ----
  stageH(0);
  stageH(1);
  loadA(0, 0, afA);
  __syncthreads();                             // drains vm; LDS+regs valid

  // ---- K-loop: 12 titers u = cc*3 + dw, unrolled by 2 for the A dbuf ----
  int cc = 0, dw = 0;
  auto body = [&](int u, bf16x8 (&cur)[3][2][2], bf16x8 (&nxt)[3][2][2]) {
    if (dw == 0 && cc > 0) {                   // u = 3,6,9
      __builtin_amdgcn_s_waitcnt(WAIT_VM12);   // drain halo; A(u) may fly
      __builtin_amdgcn_sched_barrier(0);
      __builtin_amdgcn_s_barrier();            // all waves done w/ old plane
      __builtin_amdgcn_sched_barrier(0);
      if (cc < 3) stageH(cc + 1);              // into slot (cc+1)&1
    }
    {                                          // prefetch A(u+1) -> nxt (no WAR)
      int dwn = dw + 1, ccn = cc;
      if (dwn == 3) { dwn = 0; ccn++; }
      if (u < 11) loadA(ccn, dwn, nxt);
    }
    const u16* hpl = &hB[(cc & 1) * HSTR];
    #pragma unroll
    for (int sub = 0; sub < 2; sub++) {
      const int q = sub*4 + quad;
      bf16x8 bf[10];
      #pragma unroll
      for (int n2 = 0; n2 < 10; n2++) {        // B rows 0..9 cover all dh
        const int hp = n2*18 + l15 + dw;
        bf[n2] = *(const bf16x8*)&hpl[hp*64 + ((q ^ (hp & 7)) << 3)];
      }
      #pragma unroll
      for (int dh = 0; dh < 3; dh++)
        #pragma unroll
        for (int mt = 0; mt < 2; mt++)
          #pragma unroll
          for (int nt = 0; nt < 8; nt++)
            acc[mt][nt] = __builtin_amdgcn_mfma_f32_16x16x32_bf16(
                cur[dh][sub][mt], bf[nt + dh], acc[mt][nt], 0, 0, 0);
    }
    if (++dw == 3) { dw = 0; cc++; }
  };
  #pragma unroll 1
  for (int uu = 0; uu < 12; uu += 2) {
    body(uu,     afA, afB);
    body(uu + 1, afB, afA);
  }

  const int gx = tx0 + l15;
  if (MODE == 0) {
    const float* __restrict__ bias = br ? bb : bc;
    float* __restrict__ Y = br ? Yb : Yc;
    #pragma unroll
    for (int mt = 0; mt < 2; mt++) {
      const int mloc = wv*32 + mt*16 + quad*4;          // 0..63 within block
      const int mrow = mtile*64 + mloc;                 // 0..255 global co
      const f32x4 bv = *(const f32x4*)&bias[mrow];
      float s = 0.f, sq = 0.f;
      #pragma unroll
      for (int nt = 0; nt < 8; nt++) {
        const int gy = ty0 + nt;
        f32x4 v = acc[mt][nt] + bv;
        if (gy < W && gx < W) {
          const size_t n = (size_t)(c_off[lv] + gy*W + gx);
          *(f32x4*)&Y[n*CCH + mrow] = v;
          #pragma unroll
          for (int r = 0; r < 4; r++) { s += v[r]; sq += v[r]*v[r]; }
        }
      }
      #pragma unroll
      for (int o = 1; o < 16; o <<= 1) { s += __shfl_xor(s, o); sq += __shfl_xor(sq, o); }
      if (l15 == 0) {
        const int g = mloc >> 3;               // local 8-ch GN group 0..7
        atomicAdd(&sstat[g][0], s);
        atomicAdd(&sstat[g][1], sq);
      }
    }
    __syncthreads();
    if (tid < 16) {
      const int g = tid >> 1, c = tid & 1;
      atomicAdd(&stats[((br*NLEV + lv)*32 + mtile*8 + g)*2 + c], sstat[g][c]);
    }
  } else {
    const float scl = scales[lv];
    const float stf = c_stridef[lv];
    #pragma unroll
    for (int mt = 0; mt < 2; mt++) {
      const int mr0 = mtile*64 + wv*32 + mt*16 + quad*4;
      if (mr0 >= 85) continue;
      #pragma unroll
      for (int nt = 0; nt < 8; nt++) {
        const int gy = ty0 + nt;
        if (gy >= W || gx >= W) continue;
        const size_t n = (size_t)(c_off[lv] + gy*W + gx);
        const f32x4 v = acc[mt][nt];
        #pragma unroll
        for (int r = 0; r < 4; r++) {
          const int m = mr0 + r;
          if (br == 0) {
            if (m < 80) out[n*85 + m] = v[r] + bc[m];          // logits
          } else {
            if (m < 4) {
              const float t = (v[r] + predb[m]) * scl;         // Scale module
              out[n*85 + 80 + m] = fmaxf(t, 0.f) * stf;        // relu * stride
            } else if (m == 4) {
              out[n*85 + 84] = v[r] + ioub[0];                 // iou
            }
          }
        }
      }
    }
  }
}

// GN finalize + affine + ReLU + bf16 cast into PLANAR padded layout.
// Y already includes conv bias.
__global__ __launch_bounds__(256) void gn_relu(
    const float* __restrict__ Yc, const float* __restrict__ Yb,
    const float* __restrict__ stats,
    const float* __restrict__ gwc, const float* __restrict__ gbc,
    const float* __restrict__ gwb, const float* __restrict__ gbb,
    u16* __restrict__ Xc, u16* __restrict__ Xb)
{
  const int t = blockIdx.x * 256 + threadIdx.x;
  if (t >= 2 * P_TOT * 32) return;
  const int br = t / (P_TOT * 32);
  const int r  = t - br * (P_TOT * 32);
  const int pg = r >> 5;
  const int c0 = (r & 31) << 3;
  int lv = 0;
  #pragma unroll
  for (int i = 1; i < NLEV; i++) if (pg >= c_off[i]) lv = i;
  const int pl = pg - c_off[lv];
  const int Wl = c_W[lv];
  const int g = c0 >> 3;
  const float* st = &stats[(((size_t)br*NLEV + lv)*32 + g)*2];
  const float cnt = 8.f * (float)c_HW[lv];
  const float mean = st[0] / cnt;
  const float var  = st[1] / cnt - mean*mean;
  const float rstd = rsqrtf(var + 1e-5f);
  const float* Y  = br ? Yb : Yc;
  const float* gw = br ? gwb : gwc;
  const float* gb = br ? gbb : gbc;
  u16* X = br ? Xb : Xc;
  const float* y = &Y[(size_t)pg*CCH + c0];
  const int h = pl / Wl, wi = pl - h*Wl;
  const size_t pidx = (size_t)(c_poff[lv] + (h+1)*(Wl+2) + (wi+1));
  union { u16 u[8]; uint4 v; } pk;
  #pragma unroll
  for (int i = 0; i < 8; i++) {
    const float v = (y[i] - mean)*rstd*gw[c0+i] + gb[c0+i];
    pk.u[i] = f2bf(fmaxf(v, 0.f));
  }
  *(uint4*)&X[(size_t)(c0 >> 6)*PLS + pidx*64 + (c0 & 63)] = pk.v;
}

// fp32 NCHW feats -> bf16 planar padded
__global__ __launch_bounds__(256) void feat2bf(
    const float* __restrict__ p3, const float* __restrict__ p4,
    const float* __restrict__ p5, const float* __restrict__ p6,
    const float* __restrict__ p7, u16* __restrict__ X)
{
  const int t = blockIdx.x * 256 + threadIdx.x;
  if (t >= P_TOT * 32) return;
  const int pg = t >> 5, c0 = (t & 31) << 3;
  int lv = 0;
  #pragma unroll
  for (int i = 1; i < NLEV; i++) if (pg >= c_off[i]) lv = i;
  const int pl = pg - c_off[lv];
  const float* src = lv==0 ? p3 : lv==1 ? p4 : lv==2 ? p5 : lv==3 ? p6 : p7;
  const int HW = c_HW[lv], Wl = c_W[lv];
  const int h = pl / Wl, wi = pl - h*Wl;
  const size_t pidx = (size_t)(c_poff[lv] + (h+1)*(Wl+2) + (wi+1));
  union { u16 u[8]; uint4 v; } pk;
  #pragma unroll
  for (int i = 0; i < 8; i++)
    pk.u[i] = f2bf(src[(size_t)(c0+i)*HW + pl]);
  *(uint4*)&X[(size_t)(c0 >> 6)*PLS + pidx*64 + (c0 & 63)] = pk.v;
}

// tower weights [l][co][ci][9] fp32 -> A-register packed bf16 layout:
// d = l*589824 + s*16384 + (co>>5)*2048 + (kl>>5)*1024 + ((co>>4)&1)*512
//     + ((kl>>3)&3)*128 + (co&15)*8 + (kl&7);  k = tap*256+ci, s=k>>6, kl=k&63.
__global__ __launch_bounds__(256) void wconv(
    const float* __restrict__ cw, const float* __restrict__ bw,
    u16* __restrict__ Wc, u16* __restrict__ Wb)
{
  const size_t N = (size_t)4*256*KTOT;
  const size_t t = (size_t)blockIdx.x * 256 + threadIdx.x;
  if (t >= 2*N) return;
  const float* src = (t < N) ? cw : bw;
  u16* dst = (t < N) ? Wc : Wb;
  const size_t i = (t < N) ? t : t - N;
  const size_t lc = i / KTOT;
  const int kk = (int)(i - lc*KTOT);
  const int l = (int)(lc >> 8), co = (int)(lc & 255);
  const int tap = kk >> 8, ci = kk & 255;
  const int s = kk >> 6, kl = kk & 63;
  const size_t d = (size_t)l*589824 + (size_t)s*16384 +
      (size_t)((co >> 5)*2048 + (kl >> 5)*1024 + ((co >> 4) & 1)*512 +
               ((kl >> 3) & 3)*128 + (co & 15)*8 + (kl & 7));
  dst[d] = f2bf(src[(lc*256 + ci)*9 + tap]);
}

// head weights -> A-register packed (cls: 80 rows; box: 4 pred + 1 iou),
// 128 co rows, per-stage size 8192 u16.
__global__ __launch_bounds__(256) void hconv(
    const float* __restrict__ sw, const float* __restrict__ pw,
    const float* __restrict__ iw, u16* __restrict__ Whc, u16* __restrict__ Whb)
{
  const int N = 128 * KTOT;
  const int t = blockIdx.x * 256 + threadIdx.x;
  if (t >= 2*N) return;
  const int i = (t < N) ? t : t - N;
  const int co = i / KTOT, kk = i - co*KTOT;
  const int tap = kk >> 8, ci = kk & 255;
  const int s = kk >> 6, kl = kk & 63;
  const size_t d = (size_t)s*8192 +
      (size_t)((co >> 5)*2048 + (kl >> 5)*1024 + ((co >> 4) & 1)*512 +
               ((kl >> 3) & 3)*128 + (co & 15)*8 + (kl & 7));
  float v = 0.f;
  if (t < N) {
    if (co < 80) v = sw[(co*256 + ci)*9 + tap];
    Whc[d] = f2bf(v);
  } else {
    if (co < 4)       v = pw[(co*256 + ci)*9 + tap];
    else if (co == 4) v = iw[ci*9 + tap];
    Whb[d] = f2bf(v);
  }
}

extern "C" void kernel_launch(void* const* d_in, const int* in_sizes, int n_in,
                              void* d_out, int out_size, void* d_ws, size_t ws_size,
                              hipStream_t stream)
{
  const float* p3      = (const float*)d_in[0];
  const float* p4      = (const float*)d_in[1];
  const float* p5      = (const float*)d_in[2];
  const float* p6      = (const float*)d_in[3];
  const float* p7      = (const float*)d_in[4];
  const float* cls_w   = (const float*)d_in[5];
  const float* cls_b   = (const float*)d_in[6];
  const float* cls_gw  = (const float*)d_in[7];
  const float* cls_gb  = (const float*)d_in[8];
  const float* box_w   = (const float*)d_in[9];
  const float* box_b   = (const float*)d_in[10];
  const float* box_gw  = (const float*)d_in[11];
  const float* box_gb  = (const float*)d_in[12];
  const float* score_w = (const float*)d_in[13];
  const float* score_b = (const float*)d_in[14];
  const float* pred_w  = (const float*)d_in[15];
  const float* pred_b  = (const float*)d_in[16];
  const float* iou_w   = (const float*)d_in[17];
  const float* iou_b   = (const float*)d_in[18];
  const float* scales  = (const float*)d_in[19];
  float* out = (float*)d_out;

  char* w = (char*)d_ws;
  size_t o = 0;
  auto alloc = [&](size_t b) { void* p = w + o; o += (b + 255) & ~(size_t)255; return p; };
  // X buffers + stats first: zeroed by ONE memset (all 256B multiples)
  u16*   XF = (u16*)alloc((size_t)PP_TOT*CCH*2);   // planar [4][PP_TOT][64]
  u16*   XC = (u16*)alloc((size_t)PP_TOT*CCH*2);
  u16*   XB = (u16*)alloc((size_t)PP_TOT*CCH*2);
  float* ST = (float*)alloc((size_t)4*2*NLEV*32*2*4);   // [layer][br][lv][32][2]
  u16*  WRC = (u16*)alloc((size_t)4*256*KTOT*2);
  u16*  WRB = (u16*)alloc((size_t)4*256*KTOT*2);
  u16*  WHC = (u16*)alloc((size_t)128*KTOT*2);
  u16*  WHB = (u16*)alloc((size_t)128*KTOT*2);
  float* YC = (float*)alloc((size_t)P_TOT*CCH*4);
  float* YB = (float*)alloc((size_t)P_TOT*CCH*4);

  // zero padded activation borders + all layers' GN stats in one shot
  hipMemsetAsync(XF, 0, (size_t)3*PP_TOT*CCH*2 + (size_t)4*2*NLEV*32*2*4, stream);

  wconv<<<dim3((unsigned)(((size_t)2*4*256*KTOT + 255)/256)), 256, 0, stream>>>(cls_w, box_w, WRC, WRB);
  hconv<<<dim3((2*128*KTOT + 255)/256), 256, 0, stream>>>(score_w, pred_w, iou_w, WHC, WHB);
  feat2bf<<<dim3((P_TOT*32 + 255)/256), 256, 0, stream>>>(p3, p4, p5, p6, p7, XF);

  const u16* xci = XF; const u16* xbi = XF;
  for (int l = 0; l < 4; l++) {
    float* STl = ST + (size_t)l*2*NLEV*32*2;
    gemm_conv<0><<<dim3(592), 128, 0, stream>>>(
        xci, xbi, WRC + (size_t)l*589824, WRB + (size_t)l*589824,
        cls_b + l*256, box_b + l*256, YC, YB, STl,
        nullptr, nullptr, nullptr, nullptr);
    gn_relu<<<dim3((2*P_TOT*32 + 255)/256), 256, 0, stream>>>(
        YC, YB, STl, cls_gw + l*256, cls_gb + l*256, box_gw + l*256, box_gb + l*256,
        XC, XB);
    xci = XC; xbi = XB;
  }
  gemm_conv<1><<<dim3(74, 3, 1), 128, 0, stream>>>(
      xci, xbi, WHC, WHB, score_b, nullptr, nullptr, nullptr, nullptr,
      pred_b, iou_b, scales, out);
}

// Round 6
// 327.448 us; speedup vs baseline: 1.0179x; 1.0179x over previous
//
#include <hip/hip_runtime.h>

typedef unsigned short u16;
typedef __attribute__((ext_vector_type(8))) short bf16x8;   // 8 x bf16 (4 VGPRs)
typedef __attribute__((ext_vector_type(4))) float f32x4;

#define NLEV 5
#define CCH 256
#define KTOT 2304            // 9 taps * 256 ci
#define P_TOT 8525           // sum HW
#define PP_TOT 9165          // sum (H+2)*(W+2)
#define PLS (PP_TOT*64)      // activation plane stride (u16), 4 planes of 64 ci
#define HSTR 11776           // halo LDS plane stride (u16) = 23 slabs * 512

__constant__ int   c_HW[NLEV]     = {6400, 1600, 400, 100, 25};
__constant__ int   c_W[NLEV]      = {80, 40, 20, 10, 5};    // H == W (square)
__constant__ int   c_off[NLEV]    = {0, 6400, 8000, 8400, 8500};
__constant__ int   c_poff[NLEV]   = {0, 6724, 8488, 8972, 9116};
__constant__ int   c_tls[NLEV+1]  = {0, 50, 65, 71, 73, 74};  // 16x8 tile starts
__constant__ int   c_ntx[NLEV]    = {5, 3, 2, 1, 1};          // tiles across
__constant__ float c_stridef[NLEV]= {8.f, 16.f, 32.f, 64.f, 128.f};

__device__ __forceinline__ u16 f2bf(float f){
  union { float f; unsigned u; } v; v.f = f;
  unsigned r = v.u + 0x7fffu + ((v.u >> 16) & 1u);   // RNE
  return (u16)(r >> 16);
}

// async global->LDS: 64 lanes x 16B; HW writes lane i to ldsbase + i*16.
__device__ __forceinline__ void g2l16(const u16* g, u16* l, int lane){
#if defined(__has_builtin)
#if __has_builtin(__builtin_amdgcn_global_load_lds)
  __builtin_amdgcn_global_load_lds(
      (const __attribute__((address_space(1))) unsigned int*)g,
      (__attribute__((address_space(3))) unsigned int*)l, 16, 0, 0);
  return;
#endif
#endif
  *(uint4*)(l + lane*8) = *(const uint4*)g;  // fallback: sync copy
}

// s_waitcnt imm (gfx9: vm[3:0] bits3:0, vm[5:4] bits15:14, exp[6:4], lgkm[11:8])
#define WAIT_VM12  0x0F7C   // vmcnt(12): allow this titer's A batch in flight

// ---------------------------------------------------------------------------
// R6: REGISTER BUDGET. R2-R5 all flat at ~330 with VGPR_Count pinned at
// 108-128 = the compiler's default 4-waves/EU occupancy target. The titer
// body's stated pipeline needs ~250 live VGPRs (acc 64 + A-dbuf 96 + bf 40
// + addr); squeezed into 128 the scheduler serializes ds_read->MFMA reuse
// chains, exposing ~120cyc LDS latency per MFMA group at 1.5 waves/SIMD
// (LDS 47KB caps 3 blocks/CU) -> MfmaUtil 8%, everything idle. LDS makes
// >2 waves/EU unreachable anyway, so the 128-reg squeeze buys nothing.
// Fix: amdgpu_waves_per_eu(2,2) declares the true occupancy target and
// unlocks the 256-VGPR budget; halo addresses recomputed inside stageH
// (4 calls) instead of 12 persistent per-lane pointers (-24 VGPR).
// Algorithm/math order unchanged from R5 (absmax must stay 0.625):
// 12 titers u=(cc,dw); B rows 0..9 ds_read once per sub, reused across 3
// dh taps; A frags double-buffered from global (afA/afB, static indices);
// halo plane LDS dbuf, barriers at u=3,6,9 with WAIT_VM12 (in-order vmem
// retirement proves the previous stageH landed). 1-D tower grid 592=74*8
// keeps the (mtile,br) weight slice XCD-resident (R5).
// MODE 0: towers, grid (592), 128 thr; GN stats fused in epilogue.
// MODE 1: heads, grid (74,3,1): y=0 br0 co0-63; y=1 br0 co64-127 (m<80);
//         y=2 br1 co0-63 (pred m<4 + iou m==4).
// ---------------------------------------------------------------------------
template<int MODE>
__global__ __launch_bounds__(128)
__attribute__((amdgpu_waves_per_eu(2, 2)))
void gemm_conv(
    const u16* __restrict__ Xc, const u16* __restrict__ Xb,
    const u16* __restrict__ Wc, const u16* __restrict__ Wb,
    const float* __restrict__ bc, const float* __restrict__ bb,
    float* __restrict__ Yc, float* __restrict__ Yb,
    float* __restrict__ stats,
    const float* __restrict__ predb, const float* __restrict__ ioub,
    const float* __restrict__ scales, float* __restrict__ out)
{
  __shared__ u16 hB[2*HSTR];        // 47104 B: halo plane dbuf (slot = cc&1)
  __shared__ float sstat[8][2];     // 64 B

  const int bid   = blockIdx.x;
  const int ptile = (MODE == 0) ? (bid >> 3) : bid;
  const int job   = (MODE == 0) ? 0 : blockIdx.y;
  const int mtile = (MODE == 0) ? (bid & 3) : (job == 1 ? 1 : 0);
  const int br    = (MODE == 0) ? ((bid >> 2) & 1) : (job == 2 ? 1 : 0);
  int lv = 0;
  #pragma unroll
  for (int i = 1; i < NLEV; i++) if (ptile >= c_tls[i]) lv = i;
  const int tidx = ptile - c_tls[lv];
  const int ntx = c_ntx[lv];
  const int ty0 = (tidx / ntx) * 8, tx0 = (tidx - (tidx / ntx) * ntx) * 16;
  const int W = c_W[lv], wrow2 = W + 2;

  const int tid = threadIdx.x, wv = tid >> 6, ln = tid & 63;
  const int quad = ln >> 4, l15 = ln & 15;

  const u16* __restrict__ X  = br ? Xb : Xc;   // planar activations
  const u16* __restrict__ WA = br ? Wb : Wc;   // packed weights

  const int SZ = (MODE == 0) ? 16384 : 8192;   // per-stage A u16s
  const int g2 = mtile*2 + wv;                 // 32-co group index
  const u16* aln = WA + (size_t)(g2*2048 + ln*8);

  // Halo staging: addresses recomputed per call (only 4 calls) to avoid 12
  // persistent per-lane pointer pairs (-24 VGPR). Slab j = wv+2i, j>22 ->
  // idempotent dup of this wave's previous slab (exactly 12 loads/wave).
  auto stageH = [&](int plane) {
    u16* dst = &hB[(plane & 1) * HSTR];
    const size_t cof = (size_t)plane * PLS;
    #pragma unroll
    for (int i = 0; i < 12; i++) {
      int j = wv + 2*i;
      if (j > 22) j -= 2;                      // wv1,i=11 -> slab 21 (dup)
      const int item = j*64 + ln;
      int hp = item >> 3; if (hp >= 180) hp -= 180;
      const int g = item & 7;
      const int hy = hp / 18, hx = hp - hy*18;
      const int prow = c_poff[lv] + (ty0 + hy)*wrow2 + tx0 + hx;
      g2l16(X + (size_t)prow*64 + ((g ^ (hp & 7)) << 3) + cof,
            dst + j*512, ln);
    }
  };

  f32x4 acc[2][8];
  #pragma unroll
  for (int i = 0; i < 2; i++)
    #pragma unroll
    for (int j = 0; j < 8; j++) acc[i][j] = (f32x4){0.f, 0.f, 0.f, 0.f};

  // A fragment DOUBLE BUFFER: [dh][sub][mt] x2 = 96 VGPR. Static indexing
  // only (rule #20): the two sets alternate via a 2-step unrolled loop.
  bf16x8 afA[3][2][2], afB[3][2][2];
  auto loadA = [&](int cc_, int dw_, bf16x8 (&af)[3][2][2]) {
    #pragma unroll
    for (int dh = 0; dh < 3; dh++) {
      const u16* p = aln + (size_t)((dh*3 + dw_)*4 + cc_) * SZ;
      #pragma unroll
      for (int sub = 0; sub < 2; sub++)
        #pragma unroll
        for (int mt = 0; mt < 2; mt++)
          af[dh][sub][mt] = *(const bf16x8*)(p + (sub*2 + mt)*512);
    }
  };

  if (MODE == 0 && tid < 16) sstat[tid >> 1][tid & 1] = 0.f;

  // ---- prologue: halo planes 0,1 + A(0) into afA; one barrier ----
  stageH(0);
  stageH(1);
  loadA(0, 0, afA);
  __syncthreads();                             // drains vm; LDS+regs valid

  // ---- K-loop: 12 titers u = cc*3 + dw, unrolled by 2 for the A dbuf ----
  int cc = 0, dw = 0;
  auto body = [&](int u, bf16x8 (&cur)[3][2][2], bf16x8 (&nxt)[3][2][2]) {
    if (dw == 0 && cc > 0) {                   // u = 3,6,9
      __builtin_amdgcn_s_waitcnt(WAIT_VM12);   // drain halo; A(u) may fly
      __builtin_amdgcn_sched_barrier(0);
      __builtin_amdgcn_s_barrier();            // all waves done w/ old plane
      __builtin_amdgcn_sched_barrier(0);
      if (cc < 3) stageH(cc + 1);              // into slot (cc+1)&1
    }
    {                                          // prefetch A(u+1) -> nxt (no WAR)
      int dwn = dw + 1, ccn = cc;
      if (dwn == 3) { dwn = 0; ccn++; }
      if (u < 11) loadA(ccn, dwn, nxt);
    }
    const u16* hpl = &hB[(cc & 1) * HSTR];
    #pragma unroll
    for (int sub = 0; sub < 2; sub++) {
      const int q = sub*4 + quad;
      bf16x8 bf[10];
      #pragma unroll
      for (int n2 = 0; n2 < 10; n2++) {        // B rows 0..9 cover all dh
        const int hp = n2*18 + l15 + dw;
        bf[n2] = *(const bf16x8*)&hpl[hp*64 + ((q ^ (hp & 7)) << 3)];
      }
      #pragma unroll
      for (int dh = 0; dh < 3; dh++)
        #pragma unroll
        for (int mt = 0; mt < 2; mt++)
          #pragma unroll
          for (int nt = 0; nt < 8; nt++)
            acc[mt][nt] = __builtin_amdgcn_mfma_f32_16x16x32_bf16(
                cur[dh][sub][mt], bf[nt + dh], acc[mt][nt], 0, 0, 0);
    }
    if (++dw == 3) { dw = 0; cc++; }
  };
  #pragma unroll 1
  for (int uu = 0; uu < 12; uu += 2) {
    body(uu,     afA, afB);
    body(uu + 1, afB, afA);
  }

  const int gx = tx0 + l15;
  if (MODE == 0) {
    const float* __restrict__ bias = br ? bb : bc;
    float* __restrict__ Y = br ? Yb : Yc;
    #pragma unroll
    for (int mt = 0; mt < 2; mt++) {
      const int mloc = wv*32 + mt*16 + quad*4;          // 0..63 within block
      const int mrow = mtile*64 + mloc;                 // 0..255 global co
      const f32x4 bv = *(const f32x4*)&bias[mrow];
      float s = 0.f, sq = 0.f;
      #pragma unroll
      for (int nt = 0; nt < 8; nt++) {
        const int gy = ty0 + nt;
        f32x4 v = acc[mt][nt] + bv;
        if (gy < W && gx < W) {
          const size_t n = (size_t)(c_off[lv] + gy*W + gx);
          *(f32x4*)&Y[n*CCH + mrow] = v;
          #pragma unroll
          for (int r = 0; r < 4; r++) { s += v[r]; sq += v[r]*v[r]; }
        }
      }
      #pragma unroll
      for (int o = 1; o < 16; o <<= 1) { s += __shfl_xor(s, o); sq += __shfl_xor(sq, o); }
      if (l15 == 0) {
        const int g = mloc >> 3;               // local 8-ch GN group 0..7
        atomicAdd(&sstat[g][0], s);
        atomicAdd(&sstat[g][1], sq);
      }
    }
    __syncthreads();
    if (tid < 16) {
      const int g = tid >> 1, c = tid & 1;
      atomicAdd(&stats[((br*NLEV + lv)*32 + mtile*8 + g)*2 + c], sstat[g][c]);
    }
  } else {
    const float scl = scales[lv];
    const float stf = c_stridef[lv];
    #pragma unroll
    for (int mt = 0; mt < 2; mt++) {
      const int mr0 = mtile*64 + wv*32 + mt*16 + quad*4;
      if (mr0 >= 85) continue;
      #pragma unroll
      for (int nt = 0; nt < 8; nt++) {
        const int gy = ty0 + nt;
        if (gy >= W || gx >= W) continue;
        const size_t n = (size_t)(c_off[lv] + gy*W + gx);
        const f32x4 v = acc[mt][nt];
        #pragma unroll
        for (int r = 0; r < 4; r++) {
          const int m = mr0 + r;
          if (br == 0) {
            if (m < 80) out[n*85 + m] = v[r] + bc[m];          // logits
          } else {
            if (m < 4) {
              const float t = (v[r] + predb[m]) * scl;         // Scale module
              out[n*85 + 80 + m] = fmaxf(t, 0.f) * stf;        // relu * stride
            } else if (m == 4) {
              out[n*85 + 84] = v[r] + ioub[0];                 // iou
            }
          }
        }
      }
    }
  }
}

// GN finalize + affine + ReLU + bf16 cast into PLANAR padded layout.
// Y already includes conv bias.
__global__ __launch_bounds__(256) void gn_relu(
    const float* __restrict__ Yc, const float* __restrict__ Yb,
    const float* __restrict__ stats,
    const float* __restrict__ gwc, const float* __restrict__ gbc,
    const float* __restrict__ gwb, const float* __restrict__ gbb,
    u16* __restrict__ Xc, u16* __restrict__ Xb)
{
  const int t = blockIdx.x * 256 + threadIdx.x;
  if (t >= 2 * P_TOT * 32) return;
  const int br = t / (P_TOT * 32);
  const int r  = t - br * (P_TOT * 32);
  const int pg = r >> 5;
  const int c0 = (r & 31) << 3;
  int lv = 0;
  #pragma unroll
  for (int i = 1; i < NLEV; i++) if (pg >= c_off[i]) lv = i;
  const int pl = pg - c_off[lv];
  const int Wl = c_W[lv];
  const int g = c0 >> 3;
  const float* st = &stats[(((size_t)br*NLEV + lv)*32 + g)*2];
  const float cnt = 8.f * (float)c_HW[lv];
  const float mean = st[0] / cnt;
  const float var  = st[1] / cnt - mean*mean;
  const float rstd = rsqrtf(var + 1e-5f);
  const float* Y  = br ? Yb : Yc;
  const float* gw = br ? gwb : gwc;
  const float* gb = br ? gbb : gbc;
  u16* X = br ? Xb : Xc;
  const float* y = &Y[(size_t)pg*CCH + c0];
  const int h = pl / Wl, wi = pl - h*Wl;
  const size_t pidx = (size_t)(c_poff[lv] + (h+1)*(Wl+2) + (wi+1));
  union { u16 u[8]; uint4 v; } pk;
  #pragma unroll
  for (int i = 0; i < 8; i++) {
    const float v = (y[i] - mean)*rstd*gw[c0+i] + gb[c0+i];
    pk.u[i] = f2bf(fmaxf(v, 0.f));
  }
  *(uint4*)&X[(size_t)(c0 >> 6)*PLS + pidx*64 + (c0 & 63)] = pk.v;
}

// fp32 NCHW feats -> bf16 planar padded
__global__ __launch_bounds__(256) void feat2bf(
    const float* __restrict__ p3, const float* __restrict__ p4,
    const float* __restrict__ p5, const float* __restrict__ p6,
    const float* __restrict__ p7, u16* __restrict__ X)
{
  const int t = blockIdx.x * 256 + threadIdx.x;
  if (t >= P_TOT * 32) return;
  const int pg = t >> 5, c0 = (t & 31) << 3;
  int lv = 0;
  #pragma unroll
  for (int i = 1; i < NLEV; i++) if (pg >= c_off[i]) lv = i;
  const int pl = pg - c_off[lv];
  const float* src = lv==0 ? p3 : lv==1 ? p4 : lv==2 ? p5 : lv==3 ? p6 : p7;
  const int HW = c_HW[lv], Wl = c_W[lv];
  const int h = pl / Wl, wi = pl - h*Wl;
  const size_t pidx = (size_t)(c_poff[lv] + (h+1)*(Wl+2) + (wi+1));
  union { u16 u[8]; uint4 v; } pk;
  #pragma unroll
  for (int i = 0; i < 8; i++)
    pk.u[i] = f2bf(src[(size_t)(c0+i)*HW + pl]);
  *(uint4*)&X[(size_t)(c0 >> 6)*PLS + pidx*64 + (c0 & 63)] = pk.v;
}

// tower weights [l][co][ci][9] fp32 -> A-register packed bf16 layout:
// d = l*589824 + s*16384 + (co>>5)*2048 + (kl>>5)*1024 + ((co>>4)&1)*512
//     + ((kl>>3)&3)*128 + (co&15)*8 + (kl&7);  k = tap*256+ci, s=k>>6, kl=k&63.
__global__ __launch_bounds__(256) void wconv(
    const float* __restrict__ cw, const float* __restrict__ bw,
    u16* __restrict__ Wc, u16* __restrict__ Wb)
{
  const size_t N = (size_t)4*256*KTOT;
  const size_t t = (size_t)blockIdx.x * 256 + threadIdx.x;
  if (t >= 2*N) return;
  const float* src = (t < N) ? cw : bw;
  u16* dst = (t < N) ? Wc : Wb;
  const size_t i = (t < N) ? t : t - N;
  const size_t lc = i / KTOT;
  const int kk = (int)(i - lc*KTOT);
  const int l = (int)(lc >> 8), co = (int)(lc & 255);
  const int tap = kk >> 8, ci = kk & 255;
  const int s = kk >> 6, kl = kk & 63;
  const size_t d = (size_t)l*589824 + (size_t)s*16384 +
      (size_t)((co >> 5)*2048 + (kl >> 5)*1024 + ((co >> 4) & 1)*512 +
               ((kl >> 3) & 3)*128 + (co & 15)*8 + (kl & 7));
  dst[d] = f2bf(src[(lc*256 + ci)*9 + tap]);
}

// head weights -> A-register packed (cls: 80 rows; box: 4 pred + 1 iou),
// 128 co rows, per-stage size 8192 u16.
__global__ __launch_bounds__(256) void hconv(
    const float* __restrict__ sw, const float* __restrict__ pw,
    const float* __restrict__ iw, u16* __restrict__ Whc, u16* __restrict__ Whb)
{
  const int N = 128 * KTOT;
  const int t = blockIdx.x * 256 + threadIdx.x;
  if (t >= 2*N) return;
  const int i = (t < N) ? t : t - N;
  const int co = i / KTOT, kk = i - co*KTOT;
  const int tap = kk >> 8, ci = kk & 255;
  const int s = kk >> 6, kl = kk & 63;
  const size_t d = (size_t)s*8192 +
      (size_t)((co >> 5)*2048 + (kl >> 5)*1024 + ((co >> 4) & 1)*512 +
               ((kl >> 3) & 3)*128 + (co & 15)*8 + (kl & 7));
  float v = 0.f;
  if (t < N) {
    if (co < 80) v = sw[(co*256 + ci)*9 + tap];
    Whc[d] = f2bf(v);
  } else {
    if (co < 4)       v = pw[(co*256 + ci)*9 + tap];
    else if (co == 4) v = iw[ci*9 + tap];
    Whb[d] = f2bf(v);
  }
}

extern "C" void kernel_launch(void* const* d_in, const int* in_sizes, int n_in,
                              void* d_out, int out_size, void* d_ws, size_t ws_size,
                              hipStream_t stream)
{
  const float* p3      = (const float*)d_in[0];
  const float* p4      = (const float*)d_in[1];
  const float* p5      = (const float*)d_in[2];
  const float* p6      = (const float*)d_in[3];
  const float* p7      = (const float*)d_in[4];
  const float* cls_w   = (const float*)d_in[5];
  const float* cls_b   = (const float*)d_in[6];
  const float* cls_gw  = (const float*)d_in[7];
  const float* cls_gb  = (const float*)d_in[8];
  const float* box_w   = (const float*)d_in[9];
  const float* box_b   = (const float*)d_in[10];
  const float* box_gw  = (const float*)d_in[11];
  const float* box_gb  = (const float*)d_in[12];
  const float* score_w = (const float*)d_in[13];
  const float* score_b = (const float*)d_in[14];
  const float* pred_w  = (const float*)d_in[15];
  const float* pred_b  = (const float*)d_in[16];
  const float* iou_w   = (const float*)d_in[17];
  const float* iou_b   = (const float*)d_in[18];
  const float* scales  = (const float*)d_in[19];
  float* out = (float*)d_out;

  char* w = (char*)d_ws;
  size_t o = 0;
  auto alloc = [&](size_t b) { void* p = w + o; o += (b + 255) & ~(size_t)255; return p; };
  // X buffers + stats first: zeroed by ONE memset (all 256B multiples)
  u16*   XF = (u16*)alloc((size_t)PP_TOT*CCH*2);   // planar [4][PP_TOT][64]
  u16*   XC = (u16*)alloc((size_t)PP_TOT*CCH*2);
  u16*   XB = (u16*)alloc((size_t)PP_TOT*CCH*2);
  float* ST = (float*)alloc((size_t)4*2*NLEV*32*2*4);   // [layer][br][lv][32][2]
  u16*  WRC = (u16*)alloc((size_t)4*256*KTOT*2);
  u16*  WRB = (u16*)alloc((size_t)4*256*KTOT*2);
  u16*  WHC = (u16*)alloc((size_t)128*KTOT*2);
  u16*  WHB = (u16*)alloc((size_t)128*KTOT*2);
  float* YC = (float*)alloc((size_t)P_TOT*CCH*4);
  float* YB = (float*)alloc((size_t)P_TOT*CCH*4);

  // zero padded activation borders + all layers' GN stats in one shot
  hipMemsetAsync(XF, 0, (size_t)3*PP_TOT*CCH*2 + (size_t)4*2*NLEV*32*2*4, stream);

  wconv<<<dim3((unsigned)(((size_t)2*4*256*KTOT + 255)/256)), 256, 0, stream>>>(cls_w, box_w, WRC, WRB);
  hconv<<<dim3((2*128*KTOT + 255)/256), 256, 0, stream>>>(score_w, pred_w, iou_w, WHC, WHB);
  feat2bf<<<dim3((P_TOT*32 + 255)/256), 256, 0, stream>>>(p3, p4, p5, p6, p7, XF);

  const u16* xci = XF; const u16* xbi = XF;
  for (int l = 0; l < 4; l++) {
    float* STl = ST + (size_t)l*2*NLEV*32*2;
    gemm_conv<0><<<dim3(592), 128, 0, stream>>>(
        xci, xbi, WRC + (size_t)l*589824, WRB + (size_t)l*589824,
        cls_b + l*256, box_b + l*256, YC, YB, STl,
        nullptr, nullptr, nullptr, nullptr);
    gn_relu<<<dim3((2*P_TOT*32 + 255)/256), 256, 0, stream>>>(
        YC, YB, STl, cls_gw + l*256, cls_gb + l*256, box_gw + l*256, box_gb + l*256,
        XC, XB);
    xci = XC; xbi = XB;
  }
  gemm_conv<1><<<dim3(74, 3, 1), 128, 0, stream>>>(
      xci, xbi, WHC, WHB, score_b, nullptr, nullptr, nullptr, nullptr,
      pred_b, iou_b, scales, out);
}